// Round 4
// baseline (636.158 us; speedup 1.0000x reference)
//
#include <hip/hip_runtime.h>

// Bilinear grid sample, B=8 H=512 W=512 C=32, fp32 — two-pass, LDS-tiled.
//
// R3 post-mortem: source-binning cut FETCH 487->151 MB but time only
// 196->169 us => ~136 us floor independent of fabric bytes. R2's MLP null +
// line-touch arithmetic (42K line-misses/CU at ~1/10cy => ~175 us) point at
// the per-CU L1 miss path (MSHR-limited) as the wall, not bandwidth.
//
// This version removes gathers from the L1 path entirely:
//  pass 1: bin pixels by (batch, y0c>>1, x0c>>7) -> 8192 bins,
//          SoA entries {x,y} f32x2 + pix u32 (34.6 MB workspace).
//  pass 2: one block per bin; stage the bin's 3x129-line source tile
//          (48.4 KB) in LDS via streaming loads; gathers become ds_reads.
//          Bin->block map pins batch k to XCD k (bid&7) for L2-local halos.
//          Out stores non-temporal (write-once).
// Prediction: gs_tile ~100-135 us; null (>=160) => write-scatter is the
// floor -> roofline next.

#define NBINS   8192u
#define CAP     352u                    // mean 256, sigma 16 -> +6 sigma
#define EXY_OFF 32768u                  // gcnt: 8192*4 = 32 KB
#define EPIX_OFF (32768u + 8192u*352u*8u)
#define WS_NEED ((size_t)EPIX_OFF + (size_t)8192u*352u*4u)   // ~34.6 MB

typedef float f4_t __attribute__((ext_vector_type(4)));

__device__ __forceinline__ void bilinear_px(
    const float* __restrict__ ibase,
    float* __restrict__ out, unsigned pix, float x, float y, unsigned c)
{
    const int x0 = (int)floorf(x);
    const int y0 = (int)floorf(y);
    const int x0c = min(max(x0,     0), 511);
    const int x1c = min(max(x0 + 1, 0), 511);
    const int y0c = min(max(y0,     0), 511);
    const int y1c = min(max(y0 + 1, 0), 511);

    const float4 Ia = *reinterpret_cast<const float4*>(ibase + (unsigned)(y0c*512 + x0c)*32u + c);
    const float4 Ic = *reinterpret_cast<const float4*>(ibase + (unsigned)(y0c*512 + x1c)*32u + c);
    const float4 Ib = *reinterpret_cast<const float4*>(ibase + (unsigned)(y1c*512 + x0c)*32u + c);
    const float4 Id = *reinterpret_cast<const float4*>(ibase + (unsigned)(y1c*512 + x1c)*32u + c);

    const float wa = ((float)x1c - x) * ((float)y1c - y);
    const float wb = ((float)x1c - x) * (y - (float)y0c);
    const float wc = (x - (float)x0c) * ((float)y1c - y);
    const float wd = (x - (float)x0c) * (y - (float)y0c);

    float4 o;
    o.x = wa*Ia.x + wb*Ib.x + wc*Ic.x + wd*Id.x;
    o.y = wa*Ia.y + wb*Ib.y + wc*Ic.y + wd*Id.y;
    o.z = wa*Ia.z + wb*Ib.z + wc*Ic.z + wd*Id.z;
    o.w = wa*Ia.w + wb*Ib.w + wc*Ic.w + wd*Id.w;
    *reinterpret_cast<float4*>(out + (size_t)pix*32u + c) = o;
}

// ---------------- pass 1: bin pixels -> 8192 bins ----------------
// 2048 blocks x 256 thr, 4 px/thread. Per-pixel device atomic (8192
// counters, ~256 hits each -> modest contention).
__global__ __launch_bounds__(256) void gs_bin(
    const float* __restrict__ grid,
    const float* __restrict__ img,
    float* __restrict__ out,
    unsigned* __restrict__ gcnt,
    float2* __restrict__ exy,
    unsigned* __restrict__ epix)
{
    const unsigned tid = threadIdx.x;
    const unsigned blockbase = blockIdx.x << 10;
    const unsigned batch = blockbase >> 18;
    const float* ibase = img + (((size_t)batch << 18) * 32u);

    #pragma unroll
    for (int k = 0; k < 4; ++k) {
        const unsigned pix = blockbase + tid + ((unsigned)k << 8);
        const float2 g = *reinterpret_cast<const float2*>(grid + (size_t)pix * 2u);
        const float x = 0.5f * ((g.x + 1.0f) * 511.0f);
        const float y = 0.5f * ((g.y + 1.0f) * 511.0f);
        const int x0c = min(max((int)floorf(x), 0), 511);
        const int y0c = min(max((int)floorf(y), 0), 511);
        const unsigned bin = (batch << 10) | (((unsigned)y0c >> 1) << 2) | ((unsigned)x0c >> 7);
        const unsigned slot = atomicAdd(&gcnt[bin], 1u);
        if (slot < CAP) {
            exy[(size_t)bin * CAP + slot]  = make_float2(x, y);
            epix[(size_t)bin * CAP + slot] = pix;
        } else {
            // capacity overflow (P ~ 1e-9 per bin): compute directly
            for (unsigned c = 0; c < 32; c += 4)
                bilinear_px(ibase, out, pix, x, y, c);
        }
    }
}

// ---------------- pass 2: LDS-tiled apply ----------------
// 8192 blocks (one per bin) x 256 thr. Tile = rows [2*yb, 2*yb+2],
// cols [128*xb, 128*xb+128], clamped: 3*129 lines * 128B = 48.4 KB LDS.
// 3 blocks/CU resident (145 KB LDS) -> fill of one block overlaps
// gather-phase of the others.
__global__ __launch_bounds__(256) void gs_tile(
    const float* __restrict__ img,
    float* __restrict__ out,
    const unsigned* __restrict__ gcnt,
    const float2* __restrict__ exy,
    const unsigned* __restrict__ epix)
{
    __shared__ float tile[3 * 129 * 32];   // 12384 floats = 48.4 KB

    const unsigned bid  = blockIdx.x;
    const unsigned bin  = (bid & 7u) * 1024u + (bid >> 3);  // XCD k <- batch k
    const unsigned batch = bin >> 10;
    const unsigned yband = (bin >> 2) & 255u;
    const unsigned xband = bin & 3u;
    const int r0 = (int)(yband << 1);
    const int c0 = (int)(xband << 7);
    const unsigned tid = threadIdx.x;

    // ---- fill tile: 3096 float4, streaming, coalesced ----
    const float* ib = img + (((size_t)batch << 18) * 32u);
    float4* t4 = reinterpret_cast<float4*>(tile);
    for (unsigned f = tid; f < 3096u; f += 256u) {
        const unsigned l   = f >> 3;        // line 0..386
        const unsigned sub = f & 7u;        // float4 within line
        const unsigned row = l / 129u;      // const-div -> magic mul
        const unsigned col = l - row * 129u;
        const int gr = min(r0 + (int)row, 511);
        const int gc = min(c0 + (int)col, 511);
        t4[f] = *reinterpret_cast<const float4*>(ib + (unsigned)(gr*512 + gc)*32u + (sub << 2));
    }
    __syncthreads();

    unsigned n = gcnt[bin];
    if (n > CAP) n = CAP;

    const unsigned grp = tid >> 3;          // 32 pixels per block-iter
    const unsigned c   = (tid & 7u) << 2;   // channel start (float4)
    const size_t  base = (size_t)bin * CAP;

    for (unsigned p = grp; p < n; p += 32u) {
        const float2 e  = exy[base + p];    // 8-lane broadcast load
        const unsigned pix = epix[base + p];
        const float x = e.x, y = e.y;

        // identical clamp forms to reference (x1 = clip(x0+1), not x0c+1)
        const int x0 = (int)floorf(x);
        const int y0 = (int)floorf(y);
        const int x0c = min(max(x0,     0), 511);
        const int x1c = min(max(x0 + 1, 0), 511);
        const int y0c = min(max(y0,     0), 511);
        const int y1c = min(max(y0 + 1, 0), 511);

        // in-tile coords (guaranteed in range by the binning)
        const int lx0 = x0c - c0, lx1 = x1c - c0;
        const int ly0 = y0c - r0, ly1 = y1c - r0;

        const float4 Ia = *reinterpret_cast<const float4*>(tile + (unsigned)((ly0*129 + lx0) << 5) + c);
        const float4 Ic = *reinterpret_cast<const float4*>(tile + (unsigned)((ly0*129 + lx1) << 5) + c);
        const float4 Ib = *reinterpret_cast<const float4*>(tile + (unsigned)((ly1*129 + lx0) << 5) + c);
        const float4 Id = *reinterpret_cast<const float4*>(tile + (unsigned)((ly1*129 + lx1) << 5) + c);

        const float wa = ((float)x1c - x) * ((float)y1c - y);
        const float wb = ((float)x1c - x) * (y - (float)y0c);
        const float wc = (x - (float)x0c) * ((float)y1c - y);
        const float wd = (x - (float)x0c) * (y - (float)y0c);

        f4_t o;
        o.x = wa*Ia.x + wb*Ib.x + wc*Ic.x + wd*Id.x;
        o.y = wa*Ia.y + wb*Ib.y + wc*Ic.y + wd*Id.y;
        o.z = wa*Ia.z + wb*Ib.z + wc*Ic.z + wd*Id.z;
        o.w = wa*Ia.w + wb*Ib.w + wc*Ic.w + wd*Id.w;

        __builtin_nontemporal_store(o, reinterpret_cast<f4_t*>(out + (size_t)pix*32u + c));
    }
}

// ---------------- fallback: proven single-pass (R0) ----------------
__global__ __launch_bounds__(256) void gs_direct(
    const float* __restrict__ img,
    const float* __restrict__ grid,
    float* __restrict__ out)
{
    const unsigned gid = blockIdx.x * 256u + threadIdx.x;
    const unsigned pix = gid >> 3;
    const unsigned c   = (gid & 7u) << 2;
    const float2 g = *reinterpret_cast<const float2*>(grid + (size_t)pix * 2u);
    const float x = 0.5f * ((g.x + 1.0f) * 511.0f);
    const float y = 0.5f * ((g.y + 1.0f) * 511.0f);
    const unsigned batch = pix >> 18;
    const float* ibase = img + (((size_t)batch << 18) * 32u);
    bilinear_px(ibase, out, pix, x, y, c);
}

extern "C" void kernel_launch(void* const* d_in, const int* in_sizes, int n_in,
                              void* d_out, int out_size, void* d_ws, size_t ws_size,
                              hipStream_t stream) {
    const float* img  = (const float*)d_in[0];
    const float* grid = (const float*)d_in[1];
    float* out = (float*)d_out;

    if (d_ws != nullptr && ws_size >= WS_NEED) {
        unsigned* gcnt = (unsigned*)d_ws;
        float2*   exy  = (float2*)((char*)d_ws + EXY_OFF);
        unsigned* epix = (unsigned*)((char*)d_ws + EPIX_OFF);
        hipMemsetAsync(gcnt, 0, NBINS * sizeof(unsigned), stream);
        gs_bin<<<2048, 256, 0, stream>>>(grid, img, out, gcnt, exy, epix);
        gs_tile<<<NBINS, 256, 0, stream>>>(img, out, gcnt, exy, epix);
    } else {
        gs_direct<<<65536, 256, 0, stream>>>(img, grid, out);
    }
}

// Round 5
// 505.014 us; speedup vs baseline: 1.2597x; 1.2597x over previous
//
#include <hip/hip_runtime.h>

// Bilinear grid sample, B=8 H=512 W=512 C=32, fp32 — HYBRID schedule.
//
// Evidence through R4: (a) output-order direct kernel pinned at 196 us =
// ~30 G-lines/s on the L2-miss/fabric read path (nt-store null, 2x MLP
// null); (b) source-binned apply pinned at 169 us = random-128B-write DRAM
// cost (~3.5x sequential for 268 MB), reads nearly free (FETCH 151 MB,
// L2-resident); (c) LDS tiling worse (198 us, occupancy 31%).
// Dual-floor model: two DIFFERENT resources. This round overlaps them:
//   - odd 512-px chunks: binned by source y-band (pass 1), applied with
//     L2-local reads + scattered writes (DRAM-write-bound half).
//   - even 512-px chunks: direct output-order (fabric-read-bound half,
//     sequential writes).
//   - ONE fused dispatch, block types interleaved in groups of 8 so the
//     resident mix is always 50/50 and apply keeps bid%8 == XCD == bin%8.
// Prediction: fused ~130-165 us if floors independent; ~195-215 => shared
// cap => roofline call next round.

#define NBINS  128u
#define CAP    9472u                    // mean 8192, +14 sigma
#define ENT_OFF 4096
#define WS_NEED ((size_t)ENT_OFF + (size_t)NBINS * CAP * sizeof(float4))  // ~19.4 MB

__device__ __forceinline__ void bilinear_px(
    const float* __restrict__ ibase,   // img + batch offset
    float* __restrict__ out, unsigned pix, float x, float y, unsigned c)
{
    const int x0 = (int)floorf(x);
    const int y0 = (int)floorf(y);
    const int x0c = min(max(x0,     0), 511);
    const int x1c = min(max(x0 + 1, 0), 511);
    const int y0c = min(max(y0,     0), 511);
    const int y1c = min(max(y0 + 1, 0), 511);

    const float4 Ia = *reinterpret_cast<const float4*>(ibase + (unsigned)(y0c*512 + x0c)*32u + c);
    const float4 Ic = *reinterpret_cast<const float4*>(ibase + (unsigned)(y0c*512 + x1c)*32u + c);
    const float4 Ib = *reinterpret_cast<const float4*>(ibase + (unsigned)(y1c*512 + x0c)*32u + c);
    const float4 Id = *reinterpret_cast<const float4*>(ibase + (unsigned)(y1c*512 + x1c)*32u + c);

    const float wa = ((float)x1c - x) * ((float)y1c - y);
    const float wb = ((float)x1c - x) * (y - (float)y0c);
    const float wc = (x - (float)x0c) * ((float)y1c - y);
    const float wd = (x - (float)x0c) * (y - (float)y0c);

    float4 o;
    o.x = wa*Ia.x + wb*Ib.x + wc*Ic.x + wd*Id.x;
    o.y = wa*Ia.y + wb*Ib.y + wc*Ic.y + wd*Id.y;
    o.z = wa*Ia.z + wb*Ib.z + wc*Ic.z + wd*Id.z;
    o.w = wa*Ia.w + wb*Ib.w + wc*Ic.w + wd*Id.w;
    *reinterpret_cast<float4*>(out + (size_t)pix*32u + c) = o;
}

// ---------- pass 1: bin the ODD 512-px chunks by (batch, y-band) ----------
// 1024 blocks x 256 thr x 4 px = 1,048,576 px (half). Block b covers the
// two odd chunks of super-chunk [b*2048, (b+1)*2048). LDS histogram (R3's
// proven pattern), one global atomic per band per block.
__global__ __launch_bounds__(256) void gs_binh(
    const float* __restrict__ grid,
    const float* __restrict__ img,
    float* __restrict__ out,
    unsigned* __restrict__ gcnt,
    float4* __restrict__ entries)
{
    __shared__ unsigned lcnt[16];
    __shared__ unsigned lbase[16];
    const unsigned tid = threadIdx.x;
    if (tid < 16) lcnt[tid] = 0;
    __syncthreads();

    const unsigned scbase = blockIdx.x << 11;   // super-chunk base (2048 px)
    const unsigned batch  = scbase >> 18;       // 2048 | 262144 -> uniform

    float xs[4], ys[4];
    unsigned bandk[4], slotk[4], pixk[4];
    #pragma unroll
    for (int k = 0; k < 4; ++k) {
        const unsigned off = (k < 2) ? (512u + (unsigned)k * 256u)
                                     : (1024u + 512u + (unsigned)(k - 2) * 256u);
        const unsigned pix = scbase + off + tid;
        const float2 g = *reinterpret_cast<const float2*>(grid + (size_t)pix * 2u);
        const float x = 0.5f * ((g.x + 1.0f) * 511.0f);
        const float y = 0.5f * ((g.y + 1.0f) * 511.0f);
        const int y0c = min(max((int)floorf(y), 0), 511);
        const unsigned band = (unsigned)y0c >> 5;
        slotk[k] = atomicAdd(&lcnt[band], 1u);
        bandk[k] = band; pixk[k] = pix; xs[k] = x; ys[k] = y;
    }
    __syncthreads();
    if (tid < 16) lbase[tid] = atomicAdd(&gcnt[batch * 16u + tid], lcnt[tid]);
    __syncthreads();

    const float* ibase = img + (((size_t)batch << 18) * 32u);
    #pragma unroll
    for (int k = 0; k < 4; ++k) {
        const unsigned idx = lbase[bandk[k]] + slotk[k];
        const unsigned bin = batch * 16u + bandk[k];
        if (idx < CAP) {
            float4 e;
            e.x = xs[k]; e.y = ys[k];
            e.z = __uint_as_float(pixk[k]); e.w = 0.0f;
            entries[(size_t)bin * CAP + idx] = e;
        } else {
            // overflow (P ~ 0): compute directly
            for (unsigned c = 0; c < 32; c += 4)
                bilinear_px(ibase, out, pixk[k], xs[k], ys[k], c);
        }
    }
}

// ---------- fused pass 2: apply(odd chunks) + direct(even chunks) ----------
// 65536 blocks. Group of 16 consecutive bids = 8 apply + 8 direct, so the
// resident block mix is always ~50/50 and apply keeps bid%8 == XCD.
//   apply  (r<8):  xcd=r; 256 blocks/bin; bin = ord*8+xcd (bin%8==xcd).
//   direct (r>=8): d = g*8+(r-8) in [0,32768); 32 px of even chunk d>>4.
__global__ __launch_bounds__(256) void gs_fused(
    const float* __restrict__ img,
    const float* __restrict__ grid,
    float* __restrict__ out,
    const unsigned* __restrict__ gcnt,
    const float4* __restrict__ entries)
{
    const unsigned bid = blockIdx.x;
    const unsigned g   = bid >> 4;
    const unsigned r   = bid & 15u;
    const unsigned tid = threadIdx.x;
    const unsigned grp = tid >> 3;          // pixel group 0..31
    const unsigned c   = (tid & 7u) << 2;   // channel start (float4)

    if (r < 8u) {
        // ---- apply half: L2-local reads, scattered writes ----
        const unsigned ord      = g >> 8;       // 0..15
        const unsigned blkInBin = g & 255u;     // 0..255
        const unsigned bin      = ord * 8u + r; // bin % 8 == XCD
        const unsigned batch    = bin >> 4;

        unsigned n = gcnt[bin];
        if (n > CAP) n = CAP;

        const float* ibase = img + (((size_t)batch << 18) * 32u);
        const size_t  base = (size_t)bin * CAP;

        for (unsigned p = blkInBin * 32u + grp; p < n; p += 8192u) {
            const float4 e = entries[base + p];
            bilinear_px(ibase, out, __float_as_uint(e.z), e.x, e.y, c);
        }
    } else {
        // ---- direct half: sequential writes, fabric-bound reads ----
        const unsigned d = g * 8u + (r - 8u);          // 0..32767
        const unsigned pix = (d >> 4) * 1024u + (d & 15u) * 32u + grp; // even chunks
        const float2 gg = *reinterpret_cast<const float2*>(grid + (size_t)pix * 2u);
        const float x = 0.5f * ((gg.x + 1.0f) * 511.0f);
        const float y = 0.5f * ((gg.y + 1.0f) * 511.0f);
        const unsigned batch = pix >> 18;
        const float* ibase = img + (((size_t)batch << 18) * 32u);
        bilinear_px(ibase, out, pix, x, y, c);
    }
}

// ---------------- fallback: proven single-pass (R0) ----------------
__global__ __launch_bounds__(256) void gs_direct(
    const float* __restrict__ img,
    const float* __restrict__ grid,
    float* __restrict__ out)
{
    const unsigned gid = blockIdx.x * 256u + threadIdx.x;
    const unsigned pix = gid >> 3;
    const unsigned c   = (gid & 7u) << 2;
    const float2 g = *reinterpret_cast<const float2*>(grid + (size_t)pix * 2u);
    const float x = 0.5f * ((g.x + 1.0f) * 511.0f);
    const float y = 0.5f * ((g.y + 1.0f) * 511.0f);
    const unsigned batch = pix >> 18;
    const float* ibase = img + (((size_t)batch << 18) * 32u);
    bilinear_px(ibase, out, pix, x, y, c);
}

extern "C" void kernel_launch(void* const* d_in, const int* in_sizes, int n_in,
                              void* d_out, int out_size, void* d_ws, size_t ws_size,
                              hipStream_t stream) {
    const float* img  = (const float*)d_in[0];
    const float* grid = (const float*)d_in[1];
    float* out = (float*)d_out;

    if (d_ws != nullptr && ws_size >= WS_NEED) {
        unsigned* gcnt  = (unsigned*)d_ws;
        float4* entries = (float4*)((char*)d_ws + ENT_OFF);
        hipMemsetAsync(gcnt, 0, NBINS * sizeof(unsigned), stream);
        gs_binh<<<1024, 256, 0, stream>>>(grid, img, out, gcnt, entries);
        gs_fused<<<65536, 256, 0, stream>>>(img, grid, out, gcnt, entries);
    } else {
        gs_direct<<<65536, 256, 0, stream>>>(img, grid, out);
    }
}